// Round 1
// baseline (417.475 us; speedup 1.0000x reference)
//
#include <hip/hip_runtime.h>
#include <math.h>

#define Bn 256
#define Sn 512
#define En 768
#define IVS 772      // padded row stride for ivec (769 used)
#define G3n 2304     // 3*E

__device__ __forceinline__ float sigmoidf_(float x) { return 1.f / (1.f + expf(-x)); }

// location weighting: u (position feature), w (memory weight)
__device__ __forceinline__ void loc_uw(int s, int start, int al, int ml, float& u, float& w) {
  float uu;
  if (s < start)            uu = (float)(s - start);
  else if (s < start + al)  uu = 0.f;
  else                      uu = (float)(s - start - al + 1);
  float l = fabsf(uu);   // before: l = start-s = -uu; middle: 0; after: l = uu
  if (s < ml) { w = 1.f - l / (float)ml; u = uu; }
  else        { w = 1.f; u = 0.f; }
}

// ---------------- K1: g[b,s] = w*dot(memory[b,s,:], w_mem[:768]) + u*w_mem[768]
// one wave per (b,s) row
__global__ void k_gpre(const float* __restrict__ mem, const float* __restrict__ att_w,
                       const int* __restrict__ mlen, const int* __restrict__ llen,
                       const int* __restrict__ alen, float* __restrict__ g) {
  int gtid = blockIdx.x * blockDim.x + threadIdx.x;
  int wave = gtid >> 6;
  int lane = threadIdx.x & 63;
  if (wave >= Bn * Sn) return;
  int b = wave >> 9;           // / Sn
  int s = wave & (Sn - 1);
  const float* row = mem + (size_t)wave * En;
  float dot = 0.f;
#pragma unroll
  for (int j = 0; j < 3; ++j) {
    int d = j * 256 + lane * 4;
    float4 v  = *reinterpret_cast<const float4*>(row + d);
    float4 w4 = *reinterpret_cast<const float4*>(att_w + d);
    dot += v.x * w4.x + v.y * w4.y + v.z * w4.z + v.w * w4.w;
  }
#pragma unroll
  for (int off = 32; off; off >>= 1) dot += __shfl_xor(dot, off);
  if (lane == 0) {
    float u, w;
    loc_uw(s, llen[b], alen[b], mlen[b], u, w);
    g[wave] = w * dot + u * att_w[En];
  }
}

// ---------------- block reductions (256 threads = 4 waves)
__device__ __forceinline__ float blockMax256(float v, float* red) {
#pragma unroll
  for (int off = 32; off; off >>= 1) v = fmaxf(v, __shfl_xor(v, off));
  if ((threadIdx.x & 63) == 0) red[threadIdx.x >> 6] = v;
  __syncthreads();
  float r = fmaxf(fmaxf(red[0], red[1]), fmaxf(red[2], red[3]));
  __syncthreads();
  return r;
}
__device__ __forceinline__ float blockSum256(float v, float* red) {
#pragma unroll
  for (int off = 32; off; off >>= 1) v += __shfl_xor(v, off);
  if ((threadIdx.x & 63) == 0) red[threadIdx.x >> 6] = v;
  __syncthreads();
  float r = red[0] + red[1] + red[2] + red[3];
  __syncthreads();
  return r;
}

// ---------------- K2: softmax over S per batch; beta = alpha*w; ivec[b][768] = sum alpha*u
__global__ void k_softmax(const float* __restrict__ g, const int* __restrict__ mlen,
                          const int* __restrict__ llen, const int* __restrict__ alen,
                          float* __restrict__ beta, float* __restrict__ ivec) {
  __shared__ float red[4];
  int b = blockIdx.x, tid = threadIdx.x;
  float v0 = g[b * Sn + tid], v1 = g[b * Sn + 256 + tid];
  float M = blockMax256(fmaxf(v0, v1), red);
  float e0 = expf(v0 - M), e1 = expf(v1 - M);
  float Z = blockSum256(e0 + e1, red);
  float inv = 1.f / Z;
  int start = llen[b], al = alen[b], ml = mlen[b];
  float iu = 0.f;
#pragma unroll
  for (int j = 0; j < 2; ++j) {
    int s = tid + j * 256;
    float alpha = (j ? e1 : e0) * inv;
    float u, w;
    loc_uw(s, start, al, ml, u, w);
    beta[b * Sn + s] = alpha * w;
    iu += alpha * u;
  }
  float IU = blockSum256(iu, red);
  if (tid == 0) ivec[(size_t)b * IVS + En] = IU;
}

// ---------------- K3: partial[b][c][d] = sum_{s in chunk c} beta[b,s]*memory[b,s,d]
__global__ void k_wsum(const float* __restrict__ mem, const float* __restrict__ beta,
                       float* __restrict__ partial) {
  int bc = blockIdx.x;        // b*4 + c
  int b = bc >> 2, c = bc & 3;
  int tid = threadIdx.x;
  float a0 = 0.f, a1 = 0.f, a2 = 0.f;
  const float* base = mem + ((size_t)b * Sn + c * 128) * En;
  const float* bt = beta + b * Sn + c * 128;
#pragma unroll 4
  for (int s = 0; s < 128; ++s) {
    float w = bt[s];
    const float* r = base + (size_t)s * En;
    a0 += w * r[tid];
    a1 += w * r[tid + 256];
    a2 += w * r[tid + 512];
  }
  float* p = partial + (size_t)bc * En;
  p[tid] = a0; p[tid + 256] = a1; p[tid + 512] = a2;
}

// ---------------- K3b: ivec[b][d] = sum_c partial[b][c][d]  (d < 768)
__global__ void k_reduce(const float* __restrict__ partial, float* __restrict__ ivec) {
  int b = blockIdx.x, tid = threadIdx.x;
#pragma unroll
  for (int j = 0; j < 3; ++j) {
    int d = tid + j * 256;
    float s = 0.f;
#pragma unroll
    for (int c = 0; c < 4; ++c) s += partial[(size_t)(b * 4 + c) * En + d];
    ivec[(size_t)b * IVS + d] = s;
  }
}

// ---------------- K4: gi[b][n] = dot(ivec[b,:769], w_ih[n,:769]) + b_ih[n]
// tiles: M=32 (batch) x N=64, Kt=32; K main loop 768, tail k=768 in epilogue
__global__ void k_gemm_gi(const float* __restrict__ ivec, const float* __restrict__ w_ih,
                          const float* __restrict__ b_ih, float* __restrict__ gi) {
  __shared__ float As[32][33];
  __shared__ float Bs[32][68];
  int n0 = blockIdx.x * 64;
  int m0 = blockIdx.y * 32;
  int tid = threadIdx.x;
  int tx = tid & 15, ty = tid >> 4;
  float acc[2][4] = {};
  for (int k0 = 0; k0 < En; k0 += 32) {
    int k = tid & 31, r = tid >> 5;
#pragma unroll
    for (int i = 0; i < 4; ++i)
      As[k][r + 8 * i] = ivec[(size_t)(m0 + r + 8 * i) * IVS + k0 + k];
#pragma unroll
    for (int i = 0; i < 8; ++i)
      Bs[k][r + 8 * i] = w_ih[(size_t)(n0 + r + 8 * i) * 769 + k0 + k];
    __syncthreads();
#pragma unroll
    for (int kk = 0; kk < 32; ++kk) {
      float a0 = As[kk][ty * 2], a1 = As[kk][ty * 2 + 1];
      float b0 = Bs[kk][tx * 4], b1 = Bs[kk][tx * 4 + 1];
      float b2 = Bs[kk][tx * 4 + 2], b3 = Bs[kk][tx * 4 + 3];
      acc[0][0] += a0 * b0; acc[0][1] += a0 * b1; acc[0][2] += a0 * b2; acc[0][3] += a0 * b3;
      acc[1][0] += a1 * b0; acc[1][1] += a1 * b1; acc[1][2] += a1 * b2; acc[1][3] += a1 * b3;
    }
    __syncthreads();
  }
  int m = m0 + ty * 2, n = n0 + tx * 4;
  float au0 = ivec[(size_t)m * IVS + En], au1 = ivec[(size_t)(m + 1) * IVS + En];
#pragma unroll
  for (int j = 0; j < 4; ++j) {
    float wn = w_ih[(size_t)(n + j) * 769 + En];
    float bb = b_ih[n + j];
    gi[(size_t)m * G3n + n + j]       = acc[0][j] + au0 * wn + bb;
    gi[(size_t)(m + 1) * G3n + n + j] = acc[1][j] + au1 * wn + bb;
  }
}

// ---------------- hop 1 (et = 0): pure elementwise
__global__ void k_hop1(const float* __restrict__ gi, const float* __restrict__ b_hh,
                       float* __restrict__ et) {
  int b = blockIdx.y;
  int e = blockIdx.x * 256 + threadIdx.x;
  float r = sigmoidf_(gi[(size_t)b * G3n + e] + b_hh[e]);
  float z = sigmoidf_(gi[(size_t)b * G3n + En + e] + b_hh[En + e]);
  float n = tanhf(gi[(size_t)b * G3n + 2 * En + e] + r * b_hh[2 * En + e]);
  et[(size_t)b * En + e] = (1.f - z) * n;
}

// ---------------- fused hop: gh = et_in @ w_hh.T (3 gates) + GRU update
// tiles: M=32 (batch) x E=32 (gate cols), Kt=32
__global__ void k_hop(const float* __restrict__ et_in, const float* __restrict__ w_hh,
                      const float* __restrict__ gi, const float* __restrict__ b_hh,
                      float* __restrict__ et_out) {
  __shared__ float As[32][33];
  __shared__ float Bs[3][32][33];
  int e0 = blockIdx.x * 32;
  int m0 = blockIdx.y * 32;
  int tid = threadIdx.x;
  int tx = tid & 15, ty = tid >> 4;
  float accr[2][2] = {}, accz[2][2] = {}, accn[2][2] = {};
  for (int k0 = 0; k0 < En; k0 += 32) {
    int k = tid & 31, r = tid >> 5;
#pragma unroll
    for (int i = 0; i < 4; ++i)
      As[k][r + 8 * i] = et_in[(size_t)(m0 + r + 8 * i) * En + k0 + k];
#pragma unroll
    for (int gix = 0; gix < 3; ++gix)
#pragma unroll
      for (int i = 0; i < 4; ++i)
        Bs[gix][k][r + 8 * i] = w_hh[(size_t)(gix * En + e0 + r + 8 * i) * En + k0 + k];
    __syncthreads();
#pragma unroll
    for (int kk = 0; kk < 32; ++kk) {
      float a0 = As[kk][ty * 2], a1 = As[kk][ty * 2 + 1];
      float br0 = Bs[0][kk][tx * 2], br1 = Bs[0][kk][tx * 2 + 1];
      float bz0 = Bs[1][kk][tx * 2], bz1 = Bs[1][kk][tx * 2 + 1];
      float bn0 = Bs[2][kk][tx * 2], bn1 = Bs[2][kk][tx * 2 + 1];
      accr[0][0] += a0 * br0; accr[0][1] += a0 * br1;
      accr[1][0] += a1 * br0; accr[1][1] += a1 * br1;
      accz[0][0] += a0 * bz0; accz[0][1] += a0 * bz1;
      accz[1][0] += a1 * bz0; accz[1][1] += a1 * bz1;
      accn[0][0] += a0 * bn0; accn[0][1] += a0 * bn1;
      accn[1][0] += a1 * bn0; accn[1][1] += a1 * bn1;
    }
    __syncthreads();
  }
#pragma unroll
  for (int im = 0; im < 2; ++im) {
    int b = m0 + ty * 2 + im;
#pragma unroll
    for (int ie = 0; ie < 2; ++ie) {
      int e = e0 + tx * 2 + ie;
      float hr = accr[im][ie] + b_hh[e];
      float hz = accz[im][ie] + b_hh[En + e];
      float hn = accn[im][ie] + b_hh[2 * En + e];
      float rr = sigmoidf_(gi[(size_t)b * G3n + e] + hr);
      float zz = sigmoidf_(gi[(size_t)b * G3n + En + e] + hz);
      float nn = tanhf(gi[(size_t)b * G3n + 2 * En + e] + rr * hn);
      float h = et_in[(size_t)b * En + e];
      et_out[(size_t)b * En + e] = (1.f - zz) * nn + zz * h;
    }
  }
}

// ---------------- logits: one wave per batch
__global__ void k_logits(const float* __restrict__ et, const float* __restrict__ dw,
                         const float* __restrict__ db, float* __restrict__ out) {
  int gtid = blockIdx.x * blockDim.x + threadIdx.x;
  int wid = gtid >> 6;
  int lane = threadIdx.x & 63;
  if (wid >= Bn) return;
  float s0 = 0.f, s1 = 0.f, s2 = 0.f;
  for (int e = lane; e < En; e += 64) {
    float v = et[(size_t)wid * En + e];
    s0 += v * dw[e * 3 + 0];
    s1 += v * dw[e * 3 + 1];
    s2 += v * dw[e * 3 + 2];
  }
#pragma unroll
  for (int off = 32; off; off >>= 1) {
    s0 += __shfl_xor(s0, off);
    s1 += __shfl_xor(s1, off);
    s2 += __shfl_xor(s2, off);
  }
  if (lane == 0) {
    out[wid * 3 + 0] = s0 + db[0];
    out[wid * 3 + 1] = s1 + db[1];
    out[wid * 3 + 2] = s2 + db[2];
  }
}

extern "C" void kernel_launch(void* const* d_in, const int* in_sizes, int n_in,
                              void* d_out, int out_size, void* d_ws, size_t ws_size,
                              hipStream_t stream) {
  const float* memory   = (const float*)d_in[0];
  const float* att_w    = (const float*)d_in[2];
  const float* gru_w_ih = (const float*)d_in[4];
  const float* gru_w_hh = (const float*)d_in[5];
  const float* gru_b_ih = (const float*)d_in[6];
  const float* gru_b_hh = (const float*)d_in[7];
  const float* dense_w  = (const float*)d_in[8];
  const float* dense_b  = (const float*)d_in[9];
  const int* memory_len = (const int*)d_in[10];
  const int* left_len   = (const int*)d_in[11];
  const int* aspect_len = (const int*)d_in[12];
  float* out = (float*)d_out;

  float* ws   = (float*)d_ws;
  float* g    = ws;                      // Bn*Sn
  float* beta = g + Bn * Sn;             // Bn*Sn
  float* ivec = beta + Bn * Sn;          // Bn*IVS
  float* part = ivec + Bn * IVS;         // Bn*4*En
  float* gi   = part + Bn * 4 * En;      // Bn*G3n
  float* eta  = gi + (size_t)Bn * G3n;   // Bn*En
  float* etb  = eta + Bn * En;           // Bn*En

  k_gpre<<<dim3(Bn * Sn / 4), 256, 0, stream>>>(memory, att_w, memory_len, left_len, aspect_len, g);
  k_softmax<<<dim3(Bn), 256, 0, stream>>>(g, memory_len, left_len, aspect_len, beta, ivec);
  k_wsum<<<dim3(Bn * 4), 256, 0, stream>>>(memory, beta, part);
  k_reduce<<<dim3(Bn), 256, 0, stream>>>(part, ivec);
  k_gemm_gi<<<dim3(G3n / 64, Bn / 32), 256, 0, stream>>>(ivec, gru_w_ih, gru_b_ih, gi);
  k_hop1<<<dim3(En / 256, Bn), 256, 0, stream>>>(gi, gru_b_hh, eta);
  k_hop<<<dim3(En / 32, Bn / 32), 256, 0, stream>>>(eta, gru_w_hh, gi, gru_b_hh, etb);
  k_hop<<<dim3(En / 32, Bn / 32), 256, 0, stream>>>(etb, gru_w_hh, gi, gru_b_hh, eta);
  k_logits<<<dim3(Bn / 4), 256, 0, stream>>>(eta, dense_w, dense_b, out);
}

// Round 2
// 276.847 us; speedup vs baseline: 1.5080x; 1.5080x over previous
//
#include <hip/hip_runtime.h>
#include <math.h>

#define Bn 256
#define Sn 512
#define En 768
#define IVS 772      // padded row stride for ivec (769 used)
#define G3n 2304     // 3*E
#define ROWS 16      // S-rows per attention block
#define CHUNKS (Sn / ROWS)   // 32 chunks per batch

__device__ __forceinline__ float sigmoidf_(float x) { return 1.f / (1.f + expf(-x)); }

// location weighting: u (position feature), w (memory weight)
__device__ __forceinline__ void loc_uw(int s, int start, int al, int ml, float& u, float& w) {
  float uu;
  if (s < start)            uu = (float)(s - start);
  else if (s < start + al)  uu = 0.f;
  else                      uu = (float)(s - start - al + 1);
  float l = fabsf(uu);
  if (s < ml) { w = 1.f - l / (float)ml; u = uu; }
  else        { w = 1.f; u = 0.f; }
}

// ---------------- K1: fused attention partial (single pass over memory)
// block = (b, chunk c of 16 rows). Stage rows in LDS, compute g, chunk-local
// softmax numerator, weighted accumulation. Emits (m_c, z_c, iu_c, acc_c[768]).
__global__ __launch_bounds__(256) void k_attn_partial(
    const float* __restrict__ mem, const float* __restrict__ att_w,
    const int* __restrict__ mlen, const int* __restrict__ llen, const int* __restrict__ alen,
    float* __restrict__ pacc, float* __restrict__ pm,
    float* __restrict__ pz, float* __restrict__ piu) {
  __shared__ float rowsL[ROWS][En];
  __shared__ float gval[ROWS], wval[ROWS], uval[ROWS], scaleL[ROWS];
  int bc = blockIdx.x;
  int b = bc >> 5, c = bc & 31;
  int tid = threadIdx.x;
  int wv = tid >> 6, lane = tid & 63;

  float4 wreg0 = *reinterpret_cast<const float4*>(att_w + lane * 4);
  float4 wreg1 = *reinterpret_cast<const float4*>(att_w + 256 + lane * 4);
  float4 wreg2 = *reinterpret_cast<const float4*>(att_w + 512 + lane * 4);
  int start = llen[b], al = alen[b], ml = mlen[b];
  float wtail = att_w[En];

  const float* base = mem + ((size_t)b * Sn + c * ROWS) * En;
#pragma unroll
  for (int rr = 0; rr < 4; ++rr) {
    int r = wv * 4 + rr;
    const float* row = base + (size_t)r * En;
    float4 v0 = *reinterpret_cast<const float4*>(row + lane * 4);
    float4 v1 = *reinterpret_cast<const float4*>(row + 256 + lane * 4);
    float4 v2 = *reinterpret_cast<const float4*>(row + 512 + lane * 4);
    *reinterpret_cast<float4*>(&rowsL[r][lane * 4])       = v0;
    *reinterpret_cast<float4*>(&rowsL[r][256 + lane * 4]) = v1;
    *reinterpret_cast<float4*>(&rowsL[r][512 + lane * 4]) = v2;
    float dot = v0.x * wreg0.x + v0.y * wreg0.y + v0.z * wreg0.z + v0.w * wreg0.w
              + v1.x * wreg1.x + v1.y * wreg1.y + v1.z * wreg1.z + v1.w * wreg1.w
              + v2.x * wreg2.x + v2.y * wreg2.y + v2.z * wreg2.z + v2.w * wreg2.w;
#pragma unroll
    for (int off = 32; off; off >>= 1) dot += __shfl_xor(dot, off);
    if (lane == 0) {
      int s = c * ROWS + r;
      float u, w;
      loc_uw(s, start, al, ml, u, w);
      gval[r] = w * dot + u * wtail;
      wval[r] = w; uval[r] = u;
    }
  }
  __syncthreads();

  float mc = -1e30f;
#pragma unroll
  for (int s = 0; s < ROWS; ++s) mc = fmaxf(mc, gval[s]);

  if (tid < 64) {
    float e = 0.f, eu = 0.f;
    if (tid < ROWS) {
      e = expf(gval[tid] - mc);
      scaleL[tid] = e * wval[tid];
      eu = e * uval[tid];
    }
#pragma unroll
    for (int off = 32; off; off >>= 1) { e += __shfl_xor(e, off); eu += __shfl_xor(eu, off); }
    if (tid == 0) { pm[bc] = mc; pz[bc] = e; piu[bc] = eu; }
  }
  __syncthreads();

  float a0 = 0.f, a1 = 0.f, a2 = 0.f;
#pragma unroll
  for (int s = 0; s < ROWS; ++s) {
    float sc = scaleL[s];
    a0 += sc * rowsL[s][tid];
    a1 += sc * rowsL[s][tid + 256];
    a2 += sc * rowsL[s][tid + 512];
  }
  float* p = pacc + (size_t)bc * En;
  p[tid] = a0; p[tid + 256] = a1; p[tid + 512] = a2;
}

// ---------------- K2: combine 32 chunk-partials per batch -> ivec[b][769]
__global__ __launch_bounds__(256) void k_attn_combine(
    const float* __restrict__ pacc, const float* __restrict__ pm,
    const float* __restrict__ pz, const float* __restrict__ piu,
    float* __restrict__ ivec) {
  int b = blockIdx.x, tid = threadIdx.x;
  float M = -1e30f;
#pragma unroll
  for (int c = 0; c < CHUNKS; ++c) M = fmaxf(M, pm[b * CHUNKS + c]);
  float f[CHUNKS];
  float Z = 0.f, IU = 0.f;
#pragma unroll
  for (int c = 0; c < CHUNKS; ++c) {
    f[c] = expf(pm[b * CHUNKS + c] - M);
    Z  += pz[b * CHUNKS + c] * f[c];
    IU += piu[b * CHUNKS + c] * f[c];
  }
  float inv = 1.f / Z;
#pragma unroll
  for (int j = 0; j < 3; ++j) {
    int d = tid + j * 256;
    float s = 0.f;
#pragma unroll
    for (int c = 0; c < CHUNKS; ++c)
      s += f[c] * pacc[(size_t)(b * CHUNKS + c) * En + d];
    ivec[(size_t)b * IVS + d] = s * inv;
  }
  if (tid == 0) ivec[(size_t)b * IVS + En] = IU * inv;
}

// ---------------- K3: gi[b][n] = dot(ivec[b,:769], w_ih[n,:769]) + b_ih[n]
// tile M=32 x N=64, Kt=32, 256 threads (16x16), micro 2x4
__global__ __launch_bounds__(256) void k_gemm_gi(
    const float* __restrict__ ivec, const float* __restrict__ w_ih,
    const float* __restrict__ b_ih, float* __restrict__ gi) {
  __shared__ float As[32][36];
  __shared__ float Bs[32][68];
  int n0 = blockIdx.x * 64, m0 = blockIdx.y * 32;
  int tid = threadIdx.x, tx = tid & 15, ty = tid >> 4;
  int ks = tid & 31, rs = tid >> 5;
  float acc[2][4] = {};
  for (int k0 = 0; k0 < En; k0 += 32) {
#pragma unroll
    for (int i = 0; i < 4; ++i)
      As[ks][rs + 8 * i] = ivec[(size_t)(m0 + rs + 8 * i) * IVS + k0 + ks];
#pragma unroll
    for (int i = 0; i < 8; ++i)
      Bs[ks][rs + 8 * i] = w_ih[(size_t)(n0 + rs + 8 * i) * 769 + k0 + ks];
    __syncthreads();
#pragma unroll
    for (int kk = 0; kk < 32; ++kk) {
      float2 a  = *reinterpret_cast<const float2*>(&As[kk][ty * 2]);
      float4 bv = *reinterpret_cast<const float4*>(&Bs[kk][tx * 4]);
      acc[0][0] += a.x * bv.x; acc[0][1] += a.x * bv.y;
      acc[0][2] += a.x * bv.z; acc[0][3] += a.x * bv.w;
      acc[1][0] += a.y * bv.x; acc[1][1] += a.y * bv.y;
      acc[1][2] += a.y * bv.z; acc[1][3] += a.y * bv.w;
    }
    __syncthreads();
  }
  int m = m0 + ty * 2, n = n0 + tx * 4;
  float au0 = ivec[(size_t)m * IVS + En], au1 = ivec[(size_t)(m + 1) * IVS + En];
  float4 o0, o1;
  float wn0 = w_ih[(size_t)(n + 0) * 769 + En];
  float wn1 = w_ih[(size_t)(n + 1) * 769 + En];
  float wn2 = w_ih[(size_t)(n + 2) * 769 + En];
  float wn3 = w_ih[(size_t)(n + 3) * 769 + En];
  float4 bb = *reinterpret_cast<const float4*>(b_ih + n);
  o0.x = acc[0][0] + au0 * wn0 + bb.x; o0.y = acc[0][1] + au0 * wn1 + bb.y;
  o0.z = acc[0][2] + au0 * wn2 + bb.z; o0.w = acc[0][3] + au0 * wn3 + bb.w;
  o1.x = acc[1][0] + au1 * wn0 + bb.x; o1.y = acc[1][1] + au1 * wn1 + bb.y;
  o1.z = acc[1][2] + au1 * wn2 + bb.z; o1.w = acc[1][3] + au1 * wn3 + bb.w;
  *reinterpret_cast<float4*>(gi + (size_t)m * G3n + n)       = o0;
  *reinterpret_cast<float4*>(gi + (size_t)(m + 1) * G3n + n) = o1;
}

// ---------------- hop 1 (et = 0): pure elementwise
__global__ void k_hop1(const float* __restrict__ gi, const float* __restrict__ b_hh,
                       float* __restrict__ et) {
  int b = blockIdx.y;
  int e = blockIdx.x * 256 + threadIdx.x;
  float r = sigmoidf_(gi[(size_t)b * G3n + e] + b_hh[e]);
  float z = sigmoidf_(gi[(size_t)b * G3n + En + e] + b_hh[En + e]);
  float n = tanhf(gi[(size_t)b * G3n + 2 * En + e] + r * b_hh[2 * En + e]);
  et[(size_t)b * En + e] = (1.f - z) * n;
}

// ---------------- fused hop: gh = et_in @ w_hh.T (3 gates) + GRU update
// tile M=32 x E=32, Kt=32, micro 2x2x3
__global__ __launch_bounds__(256) void k_hop(
    const float* __restrict__ et_in, const float* __restrict__ w_hh,
    const float* __restrict__ gi, const float* __restrict__ b_hh,
    float* __restrict__ et_out) {
  __shared__ float As[32][36];
  __shared__ float Bs[3][32][36];
  int e0 = blockIdx.x * 32, m0 = blockIdx.y * 32;
  int tid = threadIdx.x, tx = tid & 15, ty = tid >> 4;
  int ks = tid & 31, rs = tid >> 5;
  float ar[2][2] = {}, az[2][2] = {}, an[2][2] = {};
  for (int k0 = 0; k0 < En; k0 += 32) {
#pragma unroll
    for (int i = 0; i < 4; ++i)
      As[ks][rs + 8 * i] = et_in[(size_t)(m0 + rs + 8 * i) * En + k0 + ks];
#pragma unroll
    for (int g = 0; g < 3; ++g)
#pragma unroll
      for (int i = 0; i < 4; ++i)
        Bs[g][ks][rs + 8 * i] = w_hh[(size_t)(g * En + e0 + rs + 8 * i) * En + k0 + ks];
    __syncthreads();
#pragma unroll
    for (int kk = 0; kk < 32; ++kk) {
      float2 a  = *reinterpret_cast<const float2*>(&As[kk][ty * 2]);
      float2 br = *reinterpret_cast<const float2*>(&Bs[0][kk][tx * 2]);
      float2 bz = *reinterpret_cast<const float2*>(&Bs[1][kk][tx * 2]);
      float2 bn = *reinterpret_cast<const float2*>(&Bs[2][kk][tx * 2]);
      ar[0][0] += a.x * br.x; ar[0][1] += a.x * br.y;
      ar[1][0] += a.y * br.x; ar[1][1] += a.y * br.y;
      az[0][0] += a.x * bz.x; az[0][1] += a.x * bz.y;
      az[1][0] += a.y * bz.x; az[1][1] += a.y * bz.y;
      an[0][0] += a.x * bn.x; an[0][1] += a.x * bn.y;
      an[1][0] += a.y * bn.x; an[1][1] += a.y * bn.y;
    }
    __syncthreads();
  }
#pragma unroll
  for (int im = 0; im < 2; ++im) {
    int b = m0 + ty * 2 + im;
#pragma unroll
    for (int ie = 0; ie < 2; ++ie) {
      int e = e0 + tx * 2 + ie;
      float hr = ar[im][ie] + b_hh[e];
      float hz = az[im][ie] + b_hh[En + e];
      float hn = an[im][ie] + b_hh[2 * En + e];
      float rr = sigmoidf_(gi[(size_t)b * G3n + e] + hr);
      float zz = sigmoidf_(gi[(size_t)b * G3n + En + e] + hz);
      float nn = tanhf(gi[(size_t)b * G3n + 2 * En + e] + rr * hn);
      float h = et_in[(size_t)b * En + e];
      et_out[(size_t)b * En + e] = (1.f - zz) * nn + zz * h;
    }
  }
}

// ---------------- logits: one wave per batch
__global__ void k_logits(const float* __restrict__ et, const float* __restrict__ dw,
                         const float* __restrict__ db, float* __restrict__ out) {
  int gtid = blockIdx.x * blockDim.x + threadIdx.x;
  int wid = gtid >> 6;
  int lane = threadIdx.x & 63;
  if (wid >= Bn) return;
  float s0 = 0.f, s1 = 0.f, s2 = 0.f;
  for (int e = lane; e < En; e += 64) {
    float v = et[(size_t)wid * En + e];
    s0 += v * dw[e * 3 + 0];
    s1 += v * dw[e * 3 + 1];
    s2 += v * dw[e * 3 + 2];
  }
#pragma unroll
  for (int off = 32; off; off >>= 1) {
    s0 += __shfl_xor(s0, off);
    s1 += __shfl_xor(s1, off);
    s2 += __shfl_xor(s2, off);
  }
  if (lane == 0) {
    out[wid * 3 + 0] = s0 + db[0];
    out[wid * 3 + 1] = s1 + db[1];
    out[wid * 3 + 2] = s2 + db[2];
  }
}

extern "C" void kernel_launch(void* const* d_in, const int* in_sizes, int n_in,
                              void* d_out, int out_size, void* d_ws, size_t ws_size,
                              hipStream_t stream) {
  const float* memory   = (const float*)d_in[0];
  const float* att_w    = (const float*)d_in[2];
  const float* gru_w_ih = (const float*)d_in[4];
  const float* gru_w_hh = (const float*)d_in[5];
  const float* gru_b_ih = (const float*)d_in[6];
  const float* gru_b_hh = (const float*)d_in[7];
  const float* dense_w  = (const float*)d_in[8];
  const float* dense_b  = (const float*)d_in[9];
  const int* memory_len = (const int*)d_in[10];
  const int* left_len   = (const int*)d_in[11];
  const int* aspect_len = (const int*)d_in[12];
  float* out = (float*)d_out;

  const int NPART = Bn * CHUNKS;         // 8192
  float* ws   = (float*)d_ws;
  float* pacc = ws;                       // NPART * En
  float* pm   = pacc + (size_t)NPART * En;
  float* pz   = pm + NPART;
  float* piu  = pz + NPART;
  float* ivec = piu + NPART;              // Bn * IVS
  float* gi   = ivec + Bn * IVS;          // Bn * G3n
  float* eta  = gi + (size_t)Bn * G3n;    // Bn * En
  float* etb  = eta + Bn * En;            // Bn * En

  k_attn_partial<<<dim3(NPART), 256, 0, stream>>>(memory, att_w, memory_len, left_len,
                                                  aspect_len, pacc, pm, pz, piu);
  k_attn_combine<<<dim3(Bn), 256, 0, stream>>>(pacc, pm, pz, piu, ivec);
  k_gemm_gi<<<dim3(G3n / 64, Bn / 32), 256, 0, stream>>>(ivec, gru_w_ih, gru_b_ih, gi);
  k_hop1<<<dim3(En / 256, Bn), 256, 0, stream>>>(gi, gru_b_hh, eta);
  k_hop<<<dim3(En / 32, Bn / 32), 256, 0, stream>>>(eta, gru_w_hh, gi, gru_b_hh, etb);
  k_hop<<<dim3(En / 32, Bn / 32), 256, 0, stream>>>(etb, gru_w_hh, gi, gru_b_hh, eta);
  k_logits<<<dim3(Bn / 4), 256, 0, stream>>>(eta, dense_w, dense_b, out);
}

// Round 3
// 192.893 us; speedup vs baseline: 2.1643x; 1.4352x over previous
//
#include <hip/hip_runtime.h>
#include <math.h>

#define Bn 256
#define Sn 512
#define En 768
#define G3n 2304

typedef __attribute__((ext_vector_type(8))) short short8;   // 8 bf16 in 4 VGPRs
typedef __attribute__((ext_vector_type(4))) float f32x4;

__device__ __forceinline__ float sigmoidf_(float x) { return 1.f / (1.f + expf(-x)); }

__device__ __forceinline__ unsigned short f2bf(float x) {
  unsigned int u = __builtin_bit_cast(unsigned int, x);
  u += 0x7FFFu + ((u >> 16) & 1u);          // round-to-nearest-even
  return (unsigned short)(u >> 16);
}

// location weighting: u (position feature), w (memory weight)
__device__ __forceinline__ void loc_uw(int s, int start, int al, int ml, float& u, float& w) {
  float uu;
  if (s < start)            uu = (float)(s - start);
  else if (s < start + al)  uu = 0.f;
  else                      uu = (float)(s - start - al + 1);
  float l = fabsf(uu);
  if (s < ml) { w = 1.f - l / (float)ml; u = uu; }
  else        { w = 1.f; u = 0.f; }
}

// ---------------- K0: convert GRU weights to bf16 [2304][768]
// blockIdx.y = 0 -> w_ih (row stride 769, drop tail col), 1 -> w_hh (stride 768)
__global__ __launch_bounds__(256) void k_convw(const float* __restrict__ w_ih,
                                               const float* __restrict__ w_hh,
                                               unsigned short* __restrict__ wi_bf,
                                               unsigned short* __restrict__ wh_bf) {
  int t = blockIdx.x * 256 + threadIdx.x;
  int idx = t * 8;                    // dest flat index into [2304*768)
  int r = idx / En, c = idx - r * En; // 8 elems stay within one row (768 % 8 == 0)
  const float* src;
  unsigned short* dst;
  if (blockIdx.y == 0) { src = w_ih + (size_t)r * 769 + c; dst = wi_bf + idx; }
  else                 { src = w_hh + (size_t)r * En  + c; dst = wh_bf + idx; }
  unsigned int p[4];
#pragma unroll
  for (int j = 0; j < 4; ++j) {
    unsigned int lo = f2bf(src[2 * j]);
    unsigned int hi = f2bf(src[2 * j + 1]);
    p[j] = lo | (hi << 16);
  }
  *reinterpret_cast<uint4*>(dst) = make_uint4(p[0], p[1], p[2], p[3]);
}

// ---------------- K1: full attention, one block (1024 thr / 16 waves) per batch.
// Wave wv streams rows [wv*32, wv*32+32) with online softmax in registers;
// 16 wave-partials merged in LDS. Output: ivec bf16[768] + f32 tail.
__global__ __launch_bounds__(1024) void k_attn(
    const float* __restrict__ mem, const float* __restrict__ att_w,
    const int* __restrict__ mlen, const int* __restrict__ llen, const int* __restrict__ alen,
    unsigned short* __restrict__ ivec_bf, float* __restrict__ ivtail) {
  __shared__ float accL[16][En];
  __shared__ float mL[16], zL[16], iuL[16];
  int b = blockIdx.x;
  int tid = threadIdx.x, wv = tid >> 6, lane = tid & 63;

  float4 w0 = *reinterpret_cast<const float4*>(att_w + lane * 4);
  float4 w1 = *reinterpret_cast<const float4*>(att_w + 256 + lane * 4);
  float4 w2 = *reinterpret_cast<const float4*>(att_w + 512 + lane * 4);
  float wtail = att_w[En];
  int start = llen[b], al = alen[b], ml = mlen[b];
  const float* base = mem + ((size_t)b * Sn + wv * 32) * En;

  float m = -1e30f, z = 0.f, iu = 0.f;
  float4 a0 = {0, 0, 0, 0}, a1 = {0, 0, 0, 0}, a2 = {0, 0, 0, 0};
  float4 v0 = *reinterpret_cast<const float4*>(base + lane * 4);
  float4 v1 = *reinterpret_cast<const float4*>(base + 256 + lane * 4);
  float4 v2 = *reinterpret_cast<const float4*>(base + 512 + lane * 4);

  for (int r = 0; r < 32; ++r) {
    float4 c0 = v0, c1 = v1, c2 = v2;
    if (r < 31) {
      const float* nrow = base + (size_t)(r + 1) * En;
      v0 = *reinterpret_cast<const float4*>(nrow + lane * 4);
      v1 = *reinterpret_cast<const float4*>(nrow + 256 + lane * 4);
      v2 = *reinterpret_cast<const float4*>(nrow + 512 + lane * 4);
    }
    float dot = c0.x * w0.x + c0.y * w0.y + c0.z * w0.z + c0.w * w0.w
              + c1.x * w1.x + c1.y * w1.y + c1.z * w1.z + c1.w * w1.w
              + c2.x * w2.x + c2.y * w2.y + c2.z * w2.z + c2.w * w2.w;
#pragma unroll
    for (int off = 32; off; off >>= 1) dot += __shfl_xor(dot, off);
    int s = wv * 32 + r;
    float u, w;
    loc_uw(s, start, al, ml, u, w);
    float g = w * dot + u * wtail;
    if (g > m) {                       // wave-uniform branch
      float f = expf(m - g);           // first row: exp(-inf) = 0
      z *= f; iu *= f;
      a0.x *= f; a0.y *= f; a0.z *= f; a0.w *= f;
      a1.x *= f; a1.y *= f; a1.z *= f; a1.w *= f;
      a2.x *= f; a2.y *= f; a2.z *= f; a2.w *= f;
      m = g;
    }
    float e = expf(g - m);
    z += e; iu += e * u;
    float sc = e * w;
    a0.x += sc * c0.x; a0.y += sc * c0.y; a0.z += sc * c0.z; a0.w += sc * c0.w;
    a1.x += sc * c1.x; a1.y += sc * c1.y; a1.z += sc * c1.z; a1.w += sc * c1.w;
    a2.x += sc * c2.x; a2.y += sc * c2.y; a2.z += sc * c2.z; a2.w += sc * c2.w;
  }

  *reinterpret_cast<float4*>(&accL[wv][lane * 4])       = a0;
  *reinterpret_cast<float4*>(&accL[wv][256 + lane * 4]) = a1;
  *reinterpret_cast<float4*>(&accL[wv][512 + lane * 4]) = a2;
  if (lane == 0) { mL[wv] = m; zL[wv] = z; iuL[wv] = iu; }
  __syncthreads();

  float M = mL[0];
#pragma unroll
  for (int i = 1; i < 16; ++i) M = fmaxf(M, mL[i]);
  float f[16], Z = 0.f, IU = 0.f;
#pragma unroll
  for (int i = 0; i < 16; ++i) {
    f[i] = expf(mL[i] - M);
    Z += zL[i] * f[i];
    IU += iuL[i] * f[i];
  }
  float inv = 1.f / Z;
  if (tid < En) {
    float s = 0.f;
#pragma unroll
    for (int i = 0; i < 16; ++i) s += f[i] * accL[i][tid];
    ivec_bf[(size_t)b * En + tid] = f2bf(s * inv);
  }
  if (tid == 0) ivtail[b] = IU * inv;
}

// ---------------- K2/K3: fused MFMA GEMM + GRU epilogue.
// C[256 x 3*768] = A_bf16[256x768] . W_bf16[2304x768]^T
// MODE 0: A = ivec; epilogue adds f32 tail (au * w_ih[:,768]) + b_ih, stores gi,
//         then hop-1 GRU with h=0 -> et (f32 + bf16).
// MODE 1: A = et_in_bf; epilogue reads gi, full GRU update -> et_out (f32 + bf16).
// Block: 256 thr (4 waves, 2x2), tile M=64 x E=64 x 3 gates, K-step 64.
template <int MODE>
__global__ __launch_bounds__(256) void k_fused(
    const unsigned short* __restrict__ Abf, const unsigned short* __restrict__ Wbf,
    const float* __restrict__ ivtail, const float* __restrict__ w_ih,
    const float* __restrict__ b_ih, const float* __restrict__ b_hh,
    float* __restrict__ gi, const float* __restrict__ et_in,
    float* __restrict__ et_out, unsigned short* __restrict__ et_out_bf) {
  __shared__ unsigned short As[64][72];
  __shared__ unsigned short Bs[3][64][72];
  int e0 = blockIdx.x * 64, m0 = blockIdx.y * 64;
  int tid = threadIdx.x;
  int lane = tid & 63, wv = tid >> 6;
  int wm = wv >> 1, we = wv & 1;
  int l15 = lane & 15, l4 = lane >> 4;

  f32x4 acc[2][2][3];
#pragma unroll
  for (int mi = 0; mi < 2; ++mi)
#pragma unroll
    for (int ei = 0; ei < 2; ++ei)
#pragma unroll
      for (int g = 0; g < 3; ++g) {
        acc[mi][ei][g][0] = 0.f; acc[mi][ei][g][1] = 0.f;
        acc[mi][ei][g][2] = 0.f; acc[mi][ei][g][3] = 0.f;
      }

  int arow = tid >> 3, ach = tid & 7;
  for (int k0 = 0; k0 < En; k0 += 64) {
    __syncthreads();
#pragma unroll
    for (int i = 0; i < 2; ++i) {
      int row = arow + i * 32;
      uint4 v = *reinterpret_cast<const uint4*>(Abf + (size_t)(m0 + row) * En + k0 + ach * 8);
      *reinterpret_cast<uint4*>(&As[row][ach * 8]) = v;
    }
#pragma unroll
    for (int i = 0; i < 6; ++i) {
      int idx = tid + i * 256;
      int row = idx >> 3, ch = idx & 7;
      int g = row >> 6, er = row & 63;
      uint4 v = *reinterpret_cast<const uint4*>(Wbf + (size_t)(g * En + e0 + er) * En + k0 + ch * 8);
      *reinterpret_cast<uint4*>(&Bs[g][er][ch * 8]) = v;
    }
    __syncthreads();
#pragma unroll
    for (int ks = 0; ks < 2; ++ks) {
      short8 a0 = *reinterpret_cast<const short8*>(&As[wm * 32 + l15][ks * 32 + l4 * 8]);
      short8 a1 = *reinterpret_cast<const short8*>(&As[wm * 32 + 16 + l15][ks * 32 + l4 * 8]);
#pragma unroll
      for (int g = 0; g < 3; ++g) {
        short8 b0 = *reinterpret_cast<const short8*>(&Bs[g][we * 32 + l15][ks * 32 + l4 * 8]);
        short8 b1 = *reinterpret_cast<const short8*>(&Bs[g][we * 32 + 16 + l15][ks * 32 + l4 * 8]);
        acc[0][0][g] = __builtin_amdgcn_mfma_f32_16x16x32_bf16(a0, b0, acc[0][0][g], 0, 0, 0);
        acc[0][1][g] = __builtin_amdgcn_mfma_f32_16x16x32_bf16(a0, b1, acc[0][1][g], 0, 0, 0);
        acc[1][0][g] = __builtin_amdgcn_mfma_f32_16x16x32_bf16(a1, b0, acc[1][0][g], 0, 0, 0);
        acc[1][1][g] = __builtin_amdgcn_mfma_f32_16x16x32_bf16(a1, b1, acc[1][1][g], 0, 0, 0);
      }
    }
  }

#pragma unroll
  for (int mi = 0; mi < 2; ++mi)
#pragma unroll
    for (int ei = 0; ei < 2; ++ei) {
      int ecol = e0 + we * 32 + ei * 16 + l15;
      int mbase = m0 + wm * 32 + mi * 16 + l4 * 4;
      float bhr = b_hh[ecol], bhz = b_hh[En + ecol], bhn = b_hh[2 * En + ecol];
      if (MODE == 0) {
        float wn0 = w_ih[(size_t)ecol * 769 + En];
        float wn1 = w_ih[(size_t)(En + ecol) * 769 + En];
        float wn2 = w_ih[(size_t)(2 * En + ecol) * 769 + En];
        float bi0 = b_ih[ecol], bi1 = b_ih[En + ecol], bi2 = b_ih[2 * En + ecol];
#pragma unroll
        for (int j = 0; j < 4; ++j) {
          int m = mbase + j;
          float au = ivtail[m];
          float gr = acc[mi][ei][0][j] + au * wn0 + bi0;
          float gz = acc[mi][ei][1][j] + au * wn1 + bi1;
          float gn = acc[mi][ei][2][j] + au * wn2 + bi2;
          gi[(size_t)m * G3n + ecol]            = gr;
          gi[(size_t)m * G3n + En + ecol]       = gz;
          gi[(size_t)m * G3n + 2 * En + ecol]   = gn;
          float r = sigmoidf_(gr + bhr);
          float z = sigmoidf_(gz + bhz);
          float n = tanhf(gn + r * bhn);
          float v = (1.f - z) * n;
          et_out[(size_t)m * En + ecol] = v;
          et_out_bf[(size_t)m * En + ecol] = f2bf(v);
        }
      } else {
#pragma unroll
        for (int j = 0; j < 4; ++j) {
          int m = mbase + j;
          float rr = sigmoidf_(gi[(size_t)m * G3n + ecol] + acc[mi][ei][0][j] + bhr);
          float zz = sigmoidf_(gi[(size_t)m * G3n + En + ecol] + acc[mi][ei][1][j] + bhz);
          float nn = tanhf(gi[(size_t)m * G3n + 2 * En + ecol] + rr * (acc[mi][ei][2][j] + bhn));
          float h = et_in[(size_t)m * En + ecol];
          float v = (1.f - zz) * nn + zz * h;
          et_out[(size_t)m * En + ecol] = v;
          et_out_bf[(size_t)m * En + ecol] = f2bf(v);
        }
      }
    }
}

// ---------------- logits: one wave per batch
__global__ void k_logits(const float* __restrict__ et, const float* __restrict__ dw,
                         const float* __restrict__ db, float* __restrict__ out) {
  int gtid = blockIdx.x * blockDim.x + threadIdx.x;
  int wid = gtid >> 6;
  int lane = threadIdx.x & 63;
  if (wid >= Bn) return;
  float s0 = 0.f, s1 = 0.f, s2 = 0.f;
  for (int e = lane; e < En; e += 64) {
    float v = et[(size_t)wid * En + e];
    s0 += v * dw[e * 3 + 0];
    s1 += v * dw[e * 3 + 1];
    s2 += v * dw[e * 3 + 2];
  }
#pragma unroll
  for (int off = 32; off; off >>= 1) {
    s0 += __shfl_xor(s0, off);
    s1 += __shfl_xor(s1, off);
    s2 += __shfl_xor(s2, off);
  }
  if (lane == 0) {
    out[wid * 3 + 0] = s0 + db[0];
    out[wid * 3 + 1] = s1 + db[1];
    out[wid * 3 + 2] = s2 + db[2];
  }
}

extern "C" void kernel_launch(void* const* d_in, const int* in_sizes, int n_in,
                              void* d_out, int out_size, void* d_ws, size_t ws_size,
                              hipStream_t stream) {
  const float* memory   = (const float*)d_in[0];
  const float* att_w    = (const float*)d_in[2];
  const float* gru_w_ih = (const float*)d_in[4];
  const float* gru_w_hh = (const float*)d_in[5];
  const float* gru_b_ih = (const float*)d_in[6];
  const float* gru_b_hh = (const float*)d_in[7];
  const float* dense_w  = (const float*)d_in[8];
  const float* dense_b  = (const float*)d_in[9];
  const int* memory_len = (const int*)d_in[10];
  const int* left_len   = (const int*)d_in[11];
  const int* aspect_len = (const int*)d_in[12];
  float* out = (float*)d_out;

  unsigned short* wi_bf   = (unsigned short*)d_ws;              // 2304*768
  unsigned short* wh_bf   = wi_bf + (size_t)G3n * En;           // 2304*768
  unsigned short* ivec_bf = wh_bf + (size_t)G3n * En;           // 256*768
  unsigned short* eta_bf  = ivec_bf + (size_t)Bn * En;          // 256*768
  unsigned short* etb_bf  = eta_bf + (size_t)Bn * En;           // 256*768
  float* ivtail = (float*)(etb_bf + (size_t)Bn * En);           // 256
  float* gi     = ivtail + Bn;                                  // 256*2304
  float* eta    = gi + (size_t)Bn * G3n;                        // 256*768
  float* etb    = eta + (size_t)Bn * En;                        // 256*768
  float* etc_   = etb + (size_t)Bn * En;                        // 256*768

  k_convw<<<dim3(G3n * En / 8 / 256, 2), 256, 0, stream>>>(gru_w_ih, gru_w_hh, wi_bf, wh_bf);
  k_attn<<<dim3(Bn), 1024, 0, stream>>>(memory, att_w, memory_len, left_len, aspect_len,
                                        ivec_bf, ivtail);
  k_fused<0><<<dim3(En / 64, Bn / 64), 256, 0, stream>>>(
      ivec_bf, wi_bf, ivtail, gru_w_ih, gru_b_ih, gru_b_hh, gi, nullptr, eta, eta_bf);
  k_fused<1><<<dim3(En / 64, Bn / 64), 256, 0, stream>>>(
      eta_bf, wh_bf, nullptr, nullptr, nullptr, gru_b_hh, gi, eta, etb, etb_bf);
  k_fused<1><<<dim3(En / 64, Bn / 64), 256, 0, stream>>>(
      etb_bf, wh_bf, nullptr, nullptr, nullptr, gru_b_hh, gi, etb, etc_, eta_bf);
  k_logits<<<dim3(Bn / 4), 256, 0, stream>>>(etc_, dense_w, dense_b, out);
}

// Round 4
// 126.192 us; speedup vs baseline: 3.3082x; 1.5286x over previous
//
#include <hip/hip_runtime.h>
#include <math.h>

#define Bn 256
#define Sn 512
#define En 768
#define G3n 2304

typedef __attribute__((ext_vector_type(8))) short short8;   // 8 bf16 in 4 VGPRs
typedef __attribute__((ext_vector_type(4))) float f32x4;

__device__ __forceinline__ float sigmoidf_(float x) { return 1.f / (1.f + __expf(-x)); }
__device__ __forceinline__ float tanhf_(float x) {
  float e = __expf(2.f * x);
  return (e - 1.f) / (e + 1.f);
}

__device__ __forceinline__ unsigned short f2bf(float x) {
  unsigned int u = __builtin_bit_cast(unsigned int, x);
  u += 0x7FFFu + ((u >> 16) & 1u);          // round-to-nearest-even
  return (unsigned short)(u >> 16);
}
__device__ __forceinline__ float bf2f(unsigned short u) {
  unsigned int x = ((unsigned int)u) << 16;
  return __builtin_bit_cast(float, x);
}

// location weighting: u (position feature), w (memory weight)
__device__ __forceinline__ void loc_uw(int s, int start, int al, int ml, float& u, float& w) {
  float uu;
  if (s < start)            uu = (float)(s - start);
  else if (s < start + al)  uu = 0.f;
  else                      uu = (float)(s - start - al + 1);
  float l = fabsf(uu);
  if (s < ml) { w = 1.f - l / (float)ml; u = uu; }
  else        { w = 1.f; u = 0.f; }
}

// ---------------- K0: convert GRU weights to bf16 [2304][768]
__global__ __launch_bounds__(256) void k_convw(const float* __restrict__ w_ih,
                                               const float* __restrict__ w_hh,
                                               unsigned short* __restrict__ wi_bf,
                                               unsigned short* __restrict__ wh_bf) {
  int t = blockIdx.x * 256 + threadIdx.x;
  int idx = t * 8;
  int r = idx / En, c = idx - r * En;
  const float* src;
  unsigned short* dst;
  if (blockIdx.y == 0) { src = w_ih + (size_t)r * 769 + c; dst = wi_bf + idx; }
  else                 { src = w_hh + (size_t)r * En  + c; dst = wh_bf + idx; }
  unsigned int p[4];
#pragma unroll
  for (int j = 0; j < 4; ++j) {
    unsigned int lo = f2bf(src[2 * j]);
    unsigned int hi = f2bf(src[2 * j + 1]);
    p[j] = lo | (hi << 16);
  }
  *reinterpret_cast<uint4*>(dst) = make_uint4(p[0], p[1], p[2], p[3]);
}

// ---------------- K1: attention partial. Block = (b, half of 256 rows).
// 1024 thr / 16 waves, 16 rows per wave, online softmax in registers.
// Emits unnormalized (M, Z, IU, acc[768]) per block.
__global__ __launch_bounds__(1024) void k_attn(
    const float* __restrict__ mem, const float* __restrict__ att_w,
    const int* __restrict__ mlen, const int* __restrict__ llen, const int* __restrict__ alen,
    float* __restrict__ pacc, float* __restrict__ pm,
    float* __restrict__ pz, float* __restrict__ piu) {
  __shared__ float accL[16][En];
  __shared__ float mL[16], zL[16], iuL[16];
  int bc = blockIdx.x;
  int b = bc >> 1, half = bc & 1;
  int tid = threadIdx.x, wv = tid >> 6, lane = tid & 63;

  float4 w0 = *reinterpret_cast<const float4*>(att_w + lane * 4);
  float4 w1 = *reinterpret_cast<const float4*>(att_w + 256 + lane * 4);
  float4 w2 = *reinterpret_cast<const float4*>(att_w + 512 + lane * 4);
  float wtail = att_w[En];
  int start = llen[b], al = alen[b], ml = mlen[b];
  int s0row = half * 256 + wv * 16;
  const float* base = mem + ((size_t)b * Sn + s0row) * En;

  float m = -1e30f, z = 0.f, iu = 0.f;
  float4 a0 = {0, 0, 0, 0}, a1 = {0, 0, 0, 0}, a2 = {0, 0, 0, 0};
  float4 v0 = *reinterpret_cast<const float4*>(base + lane * 4);
  float4 v1 = *reinterpret_cast<const float4*>(base + 256 + lane * 4);
  float4 v2 = *reinterpret_cast<const float4*>(base + 512 + lane * 4);

  for (int r = 0; r < 16; ++r) {
    float4 c0 = v0, c1 = v1, c2 = v2;
    if (r < 15) {
      const float* nrow = base + (size_t)(r + 1) * En;
      v0 = *reinterpret_cast<const float4*>(nrow + lane * 4);
      v1 = *reinterpret_cast<const float4*>(nrow + 256 + lane * 4);
      v2 = *reinterpret_cast<const float4*>(nrow + 512 + lane * 4);
    }
    float dot = c0.x * w0.x + c0.y * w0.y + c0.z * w0.z + c0.w * w0.w
              + c1.x * w1.x + c1.y * w1.y + c1.z * w1.z + c1.w * w1.w
              + c2.x * w2.x + c2.y * w2.y + c2.z * w2.z + c2.w * w2.w;
#pragma unroll
    for (int off = 32; off; off >>= 1) dot += __shfl_xor(dot, off);
    int s = s0row + r;
    float u, w;
    loc_uw(s, start, al, ml, u, w);
    float g = w * dot + u * wtail;
    if (g > m) {                       // wave-uniform branch
      float f = __expf(m - g);         // first row: exp(-inf) = 0
      z *= f; iu *= f;
      a0.x *= f; a0.y *= f; a0.z *= f; a0.w *= f;
      a1.x *= f; a1.y *= f; a1.z *= f; a1.w *= f;
      a2.x *= f; a2.y *= f; a2.z *= f; a2.w *= f;
      m = g;
    }
    float e = __expf(g - m);
    z += e; iu += e * u;
    float sc = e * w;
    a0.x += sc * c0.x; a0.y += sc * c0.y; a0.z += sc * c0.z; a0.w += sc * c0.w;
    a1.x += sc * c1.x; a1.y += sc * c1.y; a1.z += sc * c1.z; a1.w += sc * c1.w;
    a2.x += sc * c2.x; a2.y += sc * c2.y; a2.z += sc * c2.z; a2.w += sc * c2.w;
  }

  *reinterpret_cast<float4*>(&accL[wv][lane * 4])       = a0;
  *reinterpret_cast<float4*>(&accL[wv][256 + lane * 4]) = a1;
  *reinterpret_cast<float4*>(&accL[wv][512 + lane * 4]) = a2;
  if (lane == 0) { mL[wv] = m; zL[wv] = z; iuL[wv] = iu; }
  __syncthreads();

  float M = mL[0];
#pragma unroll
  for (int i = 1; i < 16; ++i) M = fmaxf(M, mL[i]);
  float f[16], Z = 0.f, IU = 0.f;
#pragma unroll
  for (int i = 0; i < 16; ++i) {
    f[i] = __expf(mL[i] - M);
    Z += zL[i] * f[i];
    IU += iuL[i] * f[i];
  }
  if (tid < En) {
    float s = 0.f;
#pragma unroll
    for (int i = 0; i < 16; ++i) s += f[i] * accL[i][tid];
    pacc[(size_t)bc * En + tid] = s;
  }
  if (tid == 0) { pm[bc] = M; pz[bc] = Z; piu[bc] = IU; }
}

// ---------------- K1b: merge 2 halves per batch -> ivec bf16 + tail
__global__ __launch_bounds__(256) void k_comb(
    const float* __restrict__ pacc, const float* __restrict__ pm,
    const float* __restrict__ pz, const float* __restrict__ piu,
    unsigned short* __restrict__ ivec_bf, float* __restrict__ ivtail) {
  int b = blockIdx.x, tid = threadIdx.x;
  float m0 = pm[2 * b], m1 = pm[2 * b + 1];
  float M = fmaxf(m0, m1);
  float f0 = __expf(m0 - M), f1 = __expf(m1 - M);
  float Z = pz[2 * b] * f0 + pz[2 * b + 1] * f1;
  float inv = 1.f / Z;
#pragma unroll
  for (int j = 0; j < 3; ++j) {
    int d = tid + j * 256;
    float s = f0 * pacc[(size_t)(2 * b) * En + d] + f1 * pacc[(size_t)(2 * b + 1) * En + d];
    ivec_bf[(size_t)b * En + d] = f2bf(s * inv);
  }
  if (tid == 0) ivtail[b] = (piu[2 * b] * f0 + piu[2 * b + 1] * f1) * inv;
}

// ---------------- K2/K3: fused MFMA GEMM + GRU epilogue, tile M=32 x E=32 x 3 gates.
// 256 thr = 4 waves (wm,we in 2x2); each wave one 16x16 fragment x 3 gates, K=768.
template <int MODE>
__global__ __launch_bounds__(256) void k_fused(
    const unsigned short* __restrict__ Abf, const unsigned short* __restrict__ Wbf,
    const float* __restrict__ ivtail, const float* __restrict__ w_ih,
    const float* __restrict__ b_ih, const float* __restrict__ b_hh,
    float* __restrict__ gi, const unsigned short* __restrict__ et_in_bf,
    unsigned short* __restrict__ et_out_bf) {
  __shared__ unsigned short As[32][72];
  __shared__ unsigned short Bs[3][32][72];
  int e0 = blockIdx.x * 32, m0 = blockIdx.y * 32;
  int tid = threadIdx.x;
  int lane = tid & 63, wv = tid >> 6;
  int wm = wv >> 1, we = wv & 1;
  int l15 = lane & 15, l4 = lane >> 4;

  f32x4 acc[3];
#pragma unroll
  for (int g = 0; g < 3; ++g) { acc[g][0] = 0.f; acc[g][1] = 0.f; acc[g][2] = 0.f; acc[g][3] = 0.f; }

  int arow = tid >> 3, ach = tid & 7;     // 32 rows x 8 chunks of 8 bf16
  for (int k0 = 0; k0 < En; k0 += 64) {
    __syncthreads();
    *reinterpret_cast<uint4*>(&As[arow][ach * 8]) =
        *reinterpret_cast<const uint4*>(Abf + (size_t)(m0 + arow) * En + k0 + ach * 8);
#pragma unroll
    for (int i = 0; i < 3; ++i) {
      int idx = tid + i * 256;
      int row = idx >> 3, ch = idx & 7;   // row in [0,96)
      int g = row >> 5, er = row & 31;
      *reinterpret_cast<uint4*>(&Bs[g][er][ch * 8]) =
          *reinterpret_cast<const uint4*>(Wbf + (size_t)(g * En + e0 + er) * En + k0 + ch * 8);
    }
    __syncthreads();
#pragma unroll
    for (int ks = 0; ks < 2; ++ks) {
      short8 a = *reinterpret_cast<const short8*>(&As[wm * 16 + l15][ks * 32 + l4 * 8]);
#pragma unroll
      for (int g = 0; g < 3; ++g) {
        short8 bfr = *reinterpret_cast<const short8*>(&Bs[g][we * 16 + l15][ks * 32 + l4 * 8]);
        acc[g] = __builtin_amdgcn_mfma_f32_16x16x32_bf16(a, bfr, acc[g], 0, 0, 0);
      }
    }
  }

  int ecol = e0 + we * 16 + l15;
  int mbase = m0 + wm * 16 + l4 * 4;
  float bhr = b_hh[ecol], bhz = b_hh[En + ecol], bhn = b_hh[2 * En + ecol];
  if (MODE == 0) {
    float wn0 = w_ih[(size_t)ecol * 769 + En];
    float wn1 = w_ih[(size_t)(En + ecol) * 769 + En];
    float wn2 = w_ih[(size_t)(2 * En + ecol) * 769 + En];
    float bi0 = b_ih[ecol], bi1 = b_ih[En + ecol], bi2 = b_ih[2 * En + ecol];
#pragma unroll
    for (int j = 0; j < 4; ++j) {
      int m = mbase + j;
      float au = ivtail[m];
      float gr = acc[0][j] + au * wn0 + bi0;
      float gz = acc[1][j] + au * wn1 + bi1;
      float gn = acc[2][j] + au * wn2 + bi2;
      gi[(size_t)m * G3n + ecol]          = gr;
      gi[(size_t)m * G3n + En + ecol]     = gz;
      gi[(size_t)m * G3n + 2 * En + ecol] = gn;
      float r = sigmoidf_(gr + bhr);
      float z = sigmoidf_(gz + bhz);
      float n = tanhf_(gn + r * bhn);
      et_out_bf[(size_t)m * En + ecol] = f2bf((1.f - z) * n);
    }
  } else {
#pragma unroll
    for (int j = 0; j < 4; ++j) {
      int m = mbase + j;
      float rr = sigmoidf_(gi[(size_t)m * G3n + ecol] + acc[0][j] + bhr);
      float zz = sigmoidf_(gi[(size_t)m * G3n + En + ecol] + acc[1][j] + bhz);
      float nn = tanhf_(gi[(size_t)m * G3n + 2 * En + ecol] + rr * (acc[2][j] + bhn));
      float h = bf2f(et_in_bf[(size_t)m * En + ecol]);
      et_out_bf[(size_t)m * En + ecol] = f2bf((1.f - zz) * nn + zz * h);
    }
  }
}

// ---------------- logits: one wave per batch (reads bf16 et)
__global__ void k_logits(const unsigned short* __restrict__ et_bf,
                         const float* __restrict__ dw,
                         const float* __restrict__ db, float* __restrict__ out) {
  int gtid = blockIdx.x * blockDim.x + threadIdx.x;
  int wid = gtid >> 6;
  int lane = threadIdx.x & 63;
  if (wid >= Bn) return;
  float s0 = 0.f, s1 = 0.f, s2 = 0.f;
  for (int e = lane; e < En; e += 64) {
    float v = bf2f(et_bf[(size_t)wid * En + e]);
    s0 += v * dw[e * 3 + 0];
    s1 += v * dw[e * 3 + 1];
    s2 += v * dw[e * 3 + 2];
  }
#pragma unroll
  for (int off = 32; off; off >>= 1) {
    s0 += __shfl_xor(s0, off);
    s1 += __shfl_xor(s1, off);
    s2 += __shfl_xor(s2, off);
  }
  if (lane == 0) {
    out[wid * 3 + 0] = s0 + db[0];
    out[wid * 3 + 1] = s1 + db[1];
    out[wid * 3 + 2] = s2 + db[2];
  }
}

extern "C" void kernel_launch(void* const* d_in, const int* in_sizes, int n_in,
                              void* d_out, int out_size, void* d_ws, size_t ws_size,
                              hipStream_t stream) {
  const float* memory   = (const float*)d_in[0];
  const float* att_w    = (const float*)d_in[2];
  const float* gru_w_ih = (const float*)d_in[4];
  const float* gru_w_hh = (const float*)d_in[5];
  const float* gru_b_ih = (const float*)d_in[6];
  const float* gru_b_hh = (const float*)d_in[7];
  const float* dense_w  = (const float*)d_in[8];
  const float* dense_b  = (const float*)d_in[9];
  const int* memory_len = (const int*)d_in[10];
  const int* left_len   = (const int*)d_in[11];
  const int* aspect_len = (const int*)d_in[12];
  float* out = (float*)d_out;

  unsigned short* wi_bf   = (unsigned short*)d_ws;              // 2304*768
  unsigned short* wh_bf   = wi_bf + (size_t)G3n * En;           // 2304*768
  unsigned short* ivec_bf = wh_bf + (size_t)G3n * En;           // 256*768
  unsigned short* eta_bf  = ivec_bf + (size_t)Bn * En;          // 256*768
  unsigned short* etb_bf  = eta_bf + (size_t)Bn * En;           // 256*768
  unsigned short* etc_bf  = etb_bf + (size_t)Bn * En;           // 256*768
  float* ivtail = (float*)(etc_bf + (size_t)Bn * En);           // 256
  float* pm     = ivtail + Bn;                                  // 512
  float* pz     = pm + 2 * Bn;                                  // 512
  float* piu    = pz + 2 * Bn;                                  // 512
  float* pacc   = piu + 2 * Bn;                                 // 512*768
  float* gi     = pacc + (size_t)2 * Bn * En;                   // 256*2304

  k_convw<<<dim3(G3n * En / 8 / 256, 2), 256, 0, stream>>>(gru_w_ih, gru_w_hh, wi_bf, wh_bf);
  k_attn<<<dim3(2 * Bn), 1024, 0, stream>>>(memory, att_w, memory_len, left_len, aspect_len,
                                            pacc, pm, pz, piu);
  k_comb<<<dim3(Bn), 256, 0, stream>>>(pacc, pm, pz, piu, ivec_bf, ivtail);
  k_fused<0><<<dim3(En / 32, Bn / 32), 256, 0, stream>>>(
      ivec_bf, wi_bf, ivtail, gru_w_ih, gru_b_ih, gru_b_hh, gi, nullptr, eta_bf);
  k_fused<1><<<dim3(En / 32, Bn / 32), 256, 0, stream>>>(
      eta_bf, wh_bf, nullptr, nullptr, nullptr, gru_b_hh, gi, eta_bf, etb_bf);
  k_fused<1><<<dim3(En / 32, Bn / 32), 256, 0, stream>>>(
      etb_bf, wh_bf, nullptr, nullptr, nullptr, gru_b_hh, gi, etb_bf, etc_bf);
  k_logits<<<dim3(Bn / 4), 256, 0, stream>>>(etc_bf, dense_w, dense_b, out);
}